// Round 13
// baseline (742.247 us; speedup 1.0000x reference)
//
#include <hip/hip_runtime.h>
#include <cstdint>

#define GXD 480
#define GYD 360
#define NHD 32
#define NPTS 120000
#define MPAD 120064           // NPTS padded to multiple of 256 (469*256)
#define MB128 (MPAD/128)      // 938 M-tiles of 128 rows
#define SEGR 129600           // 360*360 possible ids
#define NSEG (GXD*GYD)        // 172800
#define EPSB 1e-5f

using short8 = __attribute__((ext_vector_type(8))) short;   // 8 bf16 in 4 VGPRs
using f32x4  = __attribute__((ext_vector_type(4))) float;   // MFMA accumulator

// ---- bf16 helpers ----
__device__ __forceinline__ float bf2f(unsigned short u) {
    return __uint_as_float(((unsigned int)u) << 16);
}
__device__ __forceinline__ unsigned short f2bf(float f) {
    unsigned int u = __float_as_uint(f);
    u += 0x7fffu + ((u >> 16) & 1u);   // round-to-nearest-even
    return (unsigned short)(u >> 16);
}
// bn+relu on a packed bf16 pair; hardware RNE pack
__device__ __forceinline__ unsigned int bnrelu_pack(unsigned int wv, float sc0, float sh0,
                                                    float sc1, float sh1)
{
    float lo = __uint_as_float(wv << 16);
    float hi = __uint_as_float(wv & 0xffff0000u);
    lo = fmaxf(fmaf(lo, sc0, sh0), 0.f);
    hi = fmaxf(fmaf(hi, sc1, sh1), 0.f);
    unsigned int r;
    asm("v_cvt_pk_bf16_f32 %0, %1, %2" : "=v"(r) : "v"(lo), "v"(hi));
    return r;
}
__device__ __forceinline__ unsigned int pk_bf16(float lo, float hi)
{
    unsigned int r;
    asm("v_cvt_pk_bf16_f32 %0, %1, %2" : "=v"(r) : "v"(lo), "v"(hi));
    return r;
}
// bn+relu applied to an 8-element bf16 A-fragment (k-ascending)
__device__ __forceinline__ short8 bn_frag(short8 a, float4 s0, float4 s1,
                                          float4 h0, float4 h1)
{
    union { short8 v; uint4 u; } in, out;
    in.v = a;
    out.u.x = bnrelu_pack(in.u.x, s0.x, h0.x, s0.y, h0.y);
    out.u.y = bnrelu_pack(in.u.y, s0.z, h0.z, s0.w, h0.w);
    out.u.z = bnrelu_pack(in.u.z, s1.x, h1.x, s1.y, h1.y);
    out.u.w = bnrelu_pack(in.u.w, s1.z, h1.z, s1.w, h1.w);
    return out.v;
}

// ---- async global->LDS, 16B per lane (dest = wave-uniform base + lane*16) ----
__device__ __forceinline__ void async16(const unsigned short* g, unsigned short* l)
{
    __builtin_amdgcn_global_load_lds(
        (const __attribute__((address_space(1))) unsigned int*)g,
        (__attribute__((address_space(3))) unsigned int*)l, 16, 0, 0);
}

// ---- bn0 stats ----
__global__ __launch_bounds__(256) void bn0_stats_kernel(
    const float* __restrict__ fea, float* __restrict__ s0, float* __restrict__ q0)
{
    float s[7] = {0,0,0,0,0,0,0}, q[7] = {0,0,0,0,0,0,0};
    for (int p = blockIdx.x * 256 + threadIdx.x; p < NPTS; p += gridDim.x * 256) {
        const float* r = fea + (size_t)p * 7;
#pragma unroll
        for (int f = 0; f < 7; ++f) { float v = r[f]; s[f] += v; q[f] += v * v; }
    }
    __shared__ float red[256];
    int t = threadIdx.x;
#pragma unroll
    for (int f = 0; f < 7; ++f) {
        red[t] = s[f]; __syncthreads();
        for (int o = 128; o > 0; o >>= 1) {
            if (t < o) red[t] += red[t + o];
            __syncthreads();
        }
        if (t == 0) atomicAdd(&s0[f], red[0]);
        __syncthreads();
        red[t] = q[f]; __syncthreads();
        for (int o = 128; o > 0; o >>= 1) {
            if (t < o) red[t] += red[t + o];
            __syncthreads();
        }
        if (t == 0) atomicAdd(&q0[f], red[0]);
        __syncthreads();
    }
}

// ---- fold bn0 into W1 ----
__global__ void prep0_kernel(const float* __restrict__ s0, const float* __restrict__ q0,
                             const float* __restrict__ g0, const float* __restrict__ b0,
                             const float* __restrict__ W1, const float* __restrict__ b1,
                             float* __restrict__ W1p, float* __restrict__ b1p)
{
    __shared__ float sc[7], sh[7];
    int t = threadIdx.x;
    if (t < 7) {
        float m = s0[t] / (float)NPTS;
        float v = q0[t] / (float)NPTS - m * m;
        float inv = 1.0f / sqrtf(fmaxf(v, 0.f) + EPSB);
        sc[t] = g0[t] * inv;
        sh[t] = b0[t] - m * g0[t] * inv;
    }
    __syncthreads();
    if (t < 64) {
        float acc = b1[t];
#pragma unroll
        for (int f = 0; f < 7; ++f) {
            W1p[f * 64 + t] = W1[f * 64 + t] * sc[f];
            acc += sh[f] * W1[f * 64 + t];
        }
        b1p[t] = acc;
    }
}

// ---- weight transpose+cast: Wt[n][k] = bf16(W[k][n]) ----
__global__ __launch_bounds__(256) void wtrans_kernel(const float* __restrict__ W,
                                                     unsigned short* __restrict__ Wt,
                                                     int K, int N)
{
    int i = blockIdx.x * 256 + threadIdx.x;
    if (i < K * N) {
        int k = i / N, n = i % N;
        Wt[(size_t)n * K + k] = f2bf(W[i]);
    }
}

// ---- layer 1: y1(bf16, raw) = fea @ W1' + b1' (K=7, Nc=64) + fp32 col stats ----
__global__ __launch_bounds__(256) void layer1_kernel(
    const float* __restrict__ fea, const float* __restrict__ W1p, const float* __restrict__ b1p,
    unsigned short* __restrict__ y1, float* __restrict__ sum1, float* __restrict__ sq1)
{
    __shared__ float Wl[448], bl[64];
    __shared__ float feaL[256 * 7];
    __shared__ float colsum[64], colsq[64];
    int t = threadIdx.x;
    int p0 = blockIdx.x * 256;
    for (int i = t; i < 448; i += 256) Wl[i] = W1p[i];
    if (t < 64) { bl[t] = b1p[t]; colsum[t] = 0.f; colsq[t] = 0.f; }
    int nval7 = (NPTS - p0) * 7;                 // valid feature words in this block
    for (int i = t; i < 256 * 7; i += 256)
        feaL[i] = (i < nval7) ? fea[(size_t)p0 * 7 + i] : 0.f;
    __syncthreads();
    int cg = t & 7, pt = t >> 3;                 // 8 col-groups x 32 point-threads
    float s[8] = {}, q[8] = {};
#pragma unroll
    for (int it = 0; it < 8; ++it) {
        int row = it * 32 + pt;
        bool valid = (p0 + row) < NPTS;
        float f[7];
#pragma unroll
        for (int ff = 0; ff < 7; ++ff) f[ff] = feaL[row * 7 + ff];
        float vj[8];
#pragma unroll
        for (int j = 0; j < 8; ++j) {
            int c = cg * 8 + j;
            float v = bl[c];
#pragma unroll
            for (int ff = 0; ff < 7; ++ff) v = fmaf(f[ff], Wl[ff * 64 + c], v);
            vj[j] = v;
            if (valid) { s[j] += v; q[j] += v * v; }
        }
        uint4 ow;
        ow.x = (unsigned int)f2bf(vj[0]) | ((unsigned int)f2bf(vj[1]) << 16);
        ow.y = (unsigned int)f2bf(vj[2]) | ((unsigned int)f2bf(vj[3]) << 16);
        ow.z = (unsigned int)f2bf(vj[4]) | ((unsigned int)f2bf(vj[5]) << 16);
        ow.w = (unsigned int)f2bf(vj[6]) | ((unsigned int)f2bf(vj[7]) << 16);
        *(uint4*)(y1 + (size_t)(p0 + row) * 64 + cg * 8) = ow;
    }
#pragma unroll
    for (int off = 8; off < 64; off <<= 1) {
#pragma unroll
        for (int j = 0; j < 8; ++j) {
            s[j] += __shfl_xor(s[j], off);
            q[j] += __shfl_xor(q[j], off);
        }
    }
    if ((t & 63) < 8) {                          // one leader per cg per wave
#pragma unroll
        for (int j = 0; j < 8; ++j) {
            atomicAdd(&colsum[cg * 8 + j], s[j]);
            atomicAdd(&colsq[cg * 8 + j], q[j]);
        }
    }
    __syncthreads();
    if (t < 64) {
        atomicAdd(&sum1[t], colsum[t]);
        atomicAdd(&sq1[t], colsq[t]);
    }
}

// ---- MFMA GEMM v18: R4 cooperative structure + in-loop bn (R6/R12-verified) ----
template<int K, int NC, bool STATS>
__global__ __launch_bounds__(256) void gemm_quad(
    const unsigned short* __restrict__ A, const unsigned short* __restrict__ Wt,
    const float* __restrict__ bsum, const float* __restrict__ bsq,
    const float* __restrict__ bg, const float* __restrict__ bb,
    const float* __restrict__ bias, unsigned short* __restrict__ Y,
    float* __restrict__ osum, float* __restrict__ osq)
{
    __shared__ __align__(16) unsigned short lds[16384];   // A[2][128][32], B[2][128][32]
    __shared__ __align__(16) float scs[K], shs[K];
    __shared__ float colsum[128], colsq[128];
    int t = threadIdx.x;
    int w = t >> 6, ln = t & 63, quad = ln >> 4, lr = ln & 15;
    int wr = w >> 1, wc = w & 1;
    const int mbase = blockIdx.y * 128;
    const int cbase = blockIdx.x * 128;
    unsigned short* Asl = lds;
    unsigned short* Bsl = lds + 8192;

    for (int i = t; i < K; i += 256) {
        float m = bsum[i] / (float)NPTS;
        float v = bsq[i] / (float)NPTS - m * m;
        float inv = 1.0f / sqrtf(fmaxf(v, 0.f) + EPSB);
        scs[i] = bg[i] * inv;
        shs[i] = bb[i] - m * bg[i] * inv;
    }
    if (STATS && t < 128) { colsum[t] = 0.f; colsq[t] = 0.f; }
    __syncthreads();                               // once, before K-loop

    const int srow = w * 16 + (ln >> 2);
    const int koff = (ln & 3) * 8;

    auto stage = [&](int buf, int kt) {
#pragma unroll
        for (int half = 0; half < 2; ++half) {
            int row = half * 64 + srow;
            async16(A  + (size_t)(mbase + row) * K + kt + koff,
                    Asl + buf * 4096 + half * 2048 + w * 512 + ln * 8);
            async16(Wt + (size_t)(cbase + row) * K + kt + koff,
                    Bsl + buf * 4096 + half * 2048 + w * 512 + ln * 8);
        }
    };

    f32x4 acc[4][4];
#pragma unroll
    for (int i = 0; i < 4; ++i)
#pragma unroll
        for (int j = 0; j < 4; ++j) acc[i][j] = (f32x4){0.f, 0.f, 0.f, 0.f};

    stage(0, 0);
    stage(1, 32);

    constexpr int NR = K / 32;
#pragma unroll
    for (int r = 0; r < NR; ++r) {
        const int buf = r & 1;
        if (r + 1 < NR)
            asm volatile("s_waitcnt vmcnt(4)" ::: "memory");
        else
            asm volatile("s_waitcnt vmcnt(0)" ::: "memory");
        asm volatile("s_barrier" ::: "memory");
        short8 af[4], bfr[4];
#pragma unroll
        for (int mi = 0; mi < 4; ++mi)
            af[mi] = *(const short8*)&Asl[buf * 4096 + (wr * 64 + mi * 16 + lr) * 32 + quad * 8];
#pragma unroll
        for (int ni = 0; ni < 4; ++ni)
            bfr[ni] = *(const short8*)&Bsl[buf * 4096 + (wc * 64 + ni * 16 + lr) * 32 + quad * 8];
        const int k0 = r * 32 + quad * 8;
        float4 s0 = *(const float4*)&scs[k0];
        float4 s1 = *(const float4*)&scs[k0 + 4];
        float4 h0 = *(const float4*)&shs[k0];
        float4 h1 = *(const float4*)&shs[k0 + 4];
        asm volatile("s_waitcnt lgkmcnt(0)" ::: "memory");
        asm volatile("s_barrier" ::: "memory");
        if (r + 2 < NR)
            stage(buf, (r + 2) * 32);
#pragma unroll
        for (int mi = 0; mi < 4; ++mi)                 // bn under the stall window
            af[mi] = bn_frag(af[mi], s0, s1, h0, h1);
#pragma unroll
        for (int mi = 0; mi < 4; ++mi)
#pragma unroll
            for (int ni = 0; ni < 4; ++ni)
                acc[mi][ni] = __builtin_amdgcn_mfma_f32_16x16x32_bf16(
                    af[mi], bfr[ni], acc[mi][ni], 0, 0, 0);
    }
    __syncthreads();

    unsigned short* Cw = lds + w * 4096;
#pragma unroll
    for (int ni = 0; ni < 4; ++ni) {
        int col = ni * 16 + lr;
        float bv = bias[cbase + wc * 64 + col];
        float s = 0.f, q = 0.f;
#pragma unroll
        for (int mi = 0; mi < 4; ++mi) {
            int rb = mi * 16 + quad * 4;
#pragma unroll
            for (int r = 0; r < 4; ++r) {
                float v = acc[mi][ni][r] + bv;
                Cw[(rb + r) * 64 + col] = f2bf(v);
                if (STATS && (mbase + wr * 64 + rb + r) < NPTS) { s += v; q += v * v; }
            }
        }
        if (STATS) {
            atomicAdd(&colsum[wc * 64 + col], s);
            atomicAdd(&colsq[wc * 64 + col], q);
        }
    }
#pragma unroll
    for (int i = 0; i < 8; ++i) {
        int idx = i * 64 + ln;
        int row = idx >> 3, colq = (idx & 7) * 8;
        *(uint4*)(Y + (size_t)(mbase + wr * 64 + row) * NC + cbase + wc * 64 + colq) =
            *(const uint4*)&Cw[row * 64 + colq];
    }
    if (STATS) {
        __syncthreads();
        if (t < 128) {
            atomicAdd(&osum[blockIdx.x * 128 + t], colsum[t]);
            atomicAdd(&osq[blockIdx.x * 128 + t], colsq[t]);
        }
    }
}

// ---- sort machinery: histogram, 3-phase exclusive scan, index scatter ----
__global__ __launch_bounds__(256) void hist_kernel(const int* __restrict__ xy,
                                                   int* __restrict__ cnt)
{
    int p = blockIdx.x * 256 + threadIdx.x;
    if (p < NPTS) {
        int id = xy[(size_t)p * 2] * GYD + xy[(size_t)p * 2 + 1];
        atomicAdd(&cnt[id], 1);
    }
}

__global__ __launch_bounds__(256) void scanA_kernel(const int* __restrict__ cnt,
                                                    int* __restrict__ csum)
{
    __shared__ int red[256];
    int t = threadIdx.x, base = blockIdx.x * 2048;
    int s = 0;
    for (int i = t; i < 2048; i += 256) {
        int idx = base + i;
        if (idx < SEGR) s += cnt[idx];
    }
    red[t] = s; __syncthreads();
    for (int o = 128; o > 0; o >>= 1) { if (t < o) red[t] += red[t + o]; __syncthreads(); }
    if (t == 0) csum[blockIdx.x] = red[0];
}

__global__ void scanB_kernel(int* __restrict__ csum, int* __restrict__ offs)
{
    if (threadIdx.x == 0) {
        int run = 0;
        for (int i = 0; i < 64; ++i) { int v = csum[i]; csum[i] = run; run += v; }
        offs[SEGR] = run;
    }
}

__global__ __launch_bounds__(256) void scanC_kernel(const int* __restrict__ cnt,
                                                    const int* __restrict__ csum,
                                                    int* __restrict__ offs,
                                                    int* __restrict__ cursor)
{
    __shared__ int red[256];
    int t = threadIdx.x, base = blockIdx.x * 2048;
    int v[8]; int s = 0;
#pragma unroll
    for (int i = 0; i < 8; ++i) {
        int idx = base + t * 8 + i;
        v[i] = (idx < SEGR) ? cnt[idx] : 0;
        s += v[i];
    }
    red[t] = s; __syncthreads();
    for (int o = 1; o < 256; o <<= 1) {
        int x = (t >= o) ? red[t - o] : 0;
        __syncthreads();
        red[t] += x;
        __syncthreads();
    }
    int run = red[t] - s + csum[blockIdx.x];
#pragma unroll
    for (int i = 0; i < 8; ++i) {
        int idx = base + t * 8 + i;
        if (idx < SEGR) { offs[idx] = run; cursor[idx] = run; }
        run += v[i];
    }
}

__global__ __launch_bounds__(256) void scatter_idx_kernel(const int* __restrict__ xy,
                                                          int* __restrict__ cursor,
                                                          int* __restrict__ order)
{
    int p = blockIdx.x * 256 + threadIdx.x;
    if (p < NPTS) {
        int id = xy[(size_t)p * 2] * GYD + xy[(size_t)p * 2 + 1];
        int pos = atomicAdd(&cursor[id], 1);
        order[pos] = p;
    }
}

// ---- FUSED L4+segmax+W5+output v6: 128 cells/block, seg IN REGISTERS ----
// Halves the phase-loop count (grid 2025->1013) and deletes the LDS seg
// round-trip: max ownership is remapped to the MFMA A-fragment layout
// (thread (w,quad,lr) owns cells {w*16+lr, 64+w*16+lr} x cols
// {kt*32+quad*8..+8}), so per-cell maxes pack via v_cvt_pk directly into
// the seg A-fragments. Per phase: 3 barriers (+1 inter-chunk) vs 6.
__global__ __launch_bounds__(256) void l4seg_kernel(
    const unsigned short* __restrict__ y3, const unsigned short* __restrict__ Wt4,
    const float* __restrict__ b4, const unsigned short* __restrict__ Wt5,
    const float* __restrict__ b5, const int* __restrict__ offs,
    const int* __restrict__ ord,
    const float* __restrict__ bsum, const float* __restrict__ bsq,
    const float* __restrict__ bg, const float* __restrict__ bb,
    float* __restrict__ out)
{
    __shared__ __align__(16) unsigned short Bsl[64 * 256];    // 32 KB
    __shared__ __align__(16) unsigned short w5s[32 * 64];     // 4 KB
    __shared__ __align__(16) unsigned short y4s[64 * 72];     // 9 KB (y4 chunk)
    __shared__ float b4s[512];
    __shared__ float scs[256], shs[256];
    __shared__ int offs_s[129];
    __shared__ int osl[128];
    int t = threadIdx.x;
    int w = t >> 6, ln = t & 63, quad = ln >> 4, lr = ln & 15;
    const int c0 = blockIdx.x * 128;
    if (t < 129) { int ci = c0 + t; offs_s[t] = offs[ci < SEGR ? ci : SEGR]; }
    for (int i = t; i < 512; i += 256) b4s[i] = b4[i];
    __syncthreads();
    const int jb = offs_s[0], je = offs_s[128];
    if (jb == je) {                               // whole block empty -> zeros
#pragma unroll
        for (int m = 0; m < 2; ++m) {
            int cell = m * 64 + ln;
            if (c0 + cell < SEGR)
#pragma unroll
                for (int j = 0; j < 8; ++j)
                    out[(size_t)(w * 8 + j) * NSEG + c0 + cell] = 0.f;
        }
        return;
    }
    {   // bn3 scale/shift for the 256 input channels (one per thread)
        float m = bsum[t] / (float)NPTS;
        float v = bsq[t] / (float)NPTS - m * m;
        float inv = 1.0f / sqrtf(fmaxf(v, 0.f) + EPSB);
        scs[t] = bg[t] * inv;
        shs[t] = bb[t] - m * bg[t] * inv;
    }
    if (t < 128) { int aj = jb + t; osl[t] = ord[aj < je ? aj : je - 1]; }
    __syncthreads();

    // this thread's two cells (MFMA A-fragment layout) and their point ranges
    const int cellA = w * 16 + lr, cellB = 64 + w * 16 + lr;
    const int cjbA = offs_s[cellA], cjeA = offs_s[cellA + 1];
    const int cjbB = offs_s[cellB], cjeB = offs_s[cellB + 1];
    const int nch = (je - jb + 63) >> 6;

    // ---- resident A (bn+relu applied once): chunks 0 and 1 ----
    short8 af0[8], af1[8];
    {
        const unsigned short* Ar0 = y3 + (size_t)osl[w * 16 + lr] * 256 + quad * 8;
#pragma unroll
        for (int r = 0; r < 8; ++r) af0[r] = *(const short8*)(Ar0 + r * 32);
        const unsigned short* Ar1 = y3 + (size_t)osl[64 + w * 16 + lr] * 256 + quad * 8;
#pragma unroll
        for (int r = 0; r < 8; ++r) af1[r] = *(const short8*)(Ar1 + r * 32);
#pragma unroll
        for (int r = 0; r < 8; ++r) {
            const int k0 = r * 32 + quad * 8;
            float4 s0 = *(const float4*)&scs[k0];
            float4 s1 = *(const float4*)&scs[k0 + 4];
            float4 h0 = *(const float4*)&shs[k0];
            float4 h1 = *(const float4*)&shs[k0 + 4];
            af0[r] = bn_frag(af0[r], s0, s1, h0, h1);
            af1[r] = bn_frag(af1[r], s0, s1, h0, h1);
        }
    }

    f32x4 eacc[2][2];
#pragma unroll
    for (int m = 0; m < 2; ++m)
#pragma unroll
        for (int ni = 0; ni < 2; ++ni) eacc[m][ni] = (f32x4){0.f, 0.f, 0.f, 0.f};

    auto stageB = [&](int p) {
#pragma unroll
        for (int i = 0; i < 8; ++i) {
            int rl = w * 16 + i * 2 + (ln >> 5);            // local B row 0..63
            int cl = (ln & 31) ^ (rl & 7);                  // source logical chunk
            async16(Wt4 + (size_t)(p * 64 + rl) * 256 + cl * 8,
                    Bsl + (w * 16 + i * 2) * 256 + ln * 8);
        }
    };
    auto stageW5 = [&](int p) {
        int rl = t >> 3, cl = (t & 7) ^ (rl & 7);
        async16(Wt5 + (size_t)rl * 512 + p * 64 + cl * 8, w5s + t * 8);
    };
    auto mfma_chunk = [&](const short8* af, f32x4* acc) {
#pragma unroll
        for (int r = 0; r < 8; ++r) {
            const int cp = (r * 4 + quad) ^ (lr & 7);
#pragma unroll
            for (int ni = 0; ni < 4; ++ni) {
                short8 bfr = *(const short8*)&Bsl[(ni * 16 + lr) * 256 + cp * 8];
                acc[ni] = __builtin_amdgcn_mfma_f32_16x16x32_bf16(af[r], bfr, acc[ni], 0, 0, 0);
            }
        }
    };

    stageB(0); stageW5(0);

    for (int p = 0; p < 8; ++p) {
        asm volatile("s_waitcnt vmcnt(0)" ::: "memory");    // B(p), w5(p) landed
        asm volatile("s_barrier" ::: "memory");
        float mxvA[16], mxvB[16];
#pragma unroll
        for (int i = 0; i < 16; ++i) { mxvA[i] = -3.0e38f; mxvB[i] = -3.0e38f; }

        for (int c = 0; c < nch; ++c) {
            const int cs = jb + c * 64;
            f32x4 acc[4];
#pragma unroll
            for (int i = 0; i < 4; ++i) acc[i] = (f32x4){0.f, 0.f, 0.f, 0.f};
            if (c == 0) {
                mfma_chunk(af0, acc);
            } else if (c == 1) {
                mfma_chunk(af1, acc);
            } else {                                   // rare: >128 pts in block
                int j = cs + w * 16 + lr; if (j >= je) j = je - 1;
                const unsigned short* Ar = y3 + (size_t)ord[j] * 256 + quad * 8;
#pragma unroll
                for (int r = 0; r < 8; ++r) {
                    short8 a = *(const short8*)(Ar + r * 32);
                    const int k0 = r * 32 + quad * 8;
                    float4 s0 = *(const float4*)&scs[k0];
                    float4 s1 = *(const float4*)&scs[k0 + 4];
                    float4 h0 = *(const float4*)&shs[k0];
                    float4 h1 = *(const float4*)&shs[k0 + 4];
                    a = bn_frag(a, s0, s1, h0, h1);
                    const int cp = (r * 4 + quad) ^ (lr & 7);
#pragma unroll
                    for (int ni = 0; ni < 4; ++ni) {
                        short8 bfr = *(const short8*)&Bsl[(ni * 16 + lr) * 256 + cp * 8];
                        acc[ni] = __builtin_amdgcn_mfma_f32_16x16x32_bf16(a, bfr, acc[ni], 0, 0, 0);
                    }
                }
            }
            // y4 (+b4) -> y4s  (row = chunk-local point, col = phase col)
#pragma unroll
            for (int ni = 0; ni < 4; ++ni) {
                float bv = b4s[p * 64 + ni * 16 + lr];
#pragma unroll
                for (int rr = 0; rr < 4; ++rr)
                    y4s[(w * 16 + quad * 4 + rr) * 72 + ni * 16 + lr] = f2bf(acc[ni][rr] + bv);
            }
            asm volatile("s_waitcnt lgkmcnt(0)" ::: "memory");
            asm volatile("s_barrier" ::: "memory");     // y4s ready; all Bsl reads done
            if (c == nch - 1 && p < 7)
                stageB(p + 1);                          // Bsl free: overlap with max+seg
            // per-cell running max into the seg A-fragment registers
            {
                int lo = cjbA > cs ? cjbA : cs;
                int hi = cjeA < cs + 64 ? cjeA : cs + 64;
                for (int jj = lo; jj < hi; ++jj) {
#pragma unroll
                    for (int kt = 0; kt < 2; ++kt) {
                        const uint4 v = *(const uint4*)&y4s[(jj - cs) * 72 + kt * 32 + quad * 8];
                        unsigned int wv[4] = {v.x, v.y, v.z, v.w};
#pragma unroll
                        for (int k2 = 0; k2 < 4; ++k2) {
                            mxvA[kt * 8 + 2 * k2]     = fmaxf(mxvA[kt * 8 + 2 * k2],     bf2f((unsigned short)(wv[k2] & 0xffffu)));
                            mxvA[kt * 8 + 2 * k2 + 1] = fmaxf(mxvA[kt * 8 + 2 * k2 + 1], bf2f((unsigned short)(wv[k2] >> 16)));
                        }
                    }
                }
                lo = cjbB > cs ? cjbB : cs;
                hi = cjeB < cs + 64 ? cjeB : cs + 64;
                for (int jj = lo; jj < hi; ++jj) {
#pragma unroll
                    for (int kt = 0; kt < 2; ++kt) {
                        const uint4 v = *(const uint4*)&y4s[(jj - cs) * 72 + kt * 32 + quad * 8];
                        unsigned int wv[4] = {v.x, v.y, v.z, v.w};
#pragma unroll
                        for (int k2 = 0; k2 < 4; ++k2) {
                            mxvB[kt * 8 + 2 * k2]     = fmaxf(mxvB[kt * 8 + 2 * k2],     bf2f((unsigned short)(wv[k2] & 0xffffu)));
                            mxvB[kt * 8 + 2 * k2 + 1] = fmaxf(mxvB[kt * 8 + 2 * k2 + 1], bf2f((unsigned short)(wv[k2] >> 16)));
                        }
                    }
                }
            }
            if (c + 1 < nch)
                asm volatile("s_barrier" ::: "memory"); // y4s free for next chunk
        }
        // seg A-fragments straight from registers (empty cells -> 0)
        const bool emptyA = (cjbA == cjeA), emptyB = (cjbB == cjeB);
#pragma unroll
        for (int kt = 0; kt < 2; ++kt) {
            union { short8 v; unsigned int u[4]; } sa, sb;
#pragma unroll
            for (int j = 0; j < 4; ++j) {
                sa.u[j] = emptyA ? 0u : pk_bf16(mxvA[kt * 8 + 2 * j], mxvA[kt * 8 + 2 * j + 1]);
                sb.u[j] = emptyB ? 0u : pk_bf16(mxvB[kt * 8 + 2 * j], mxvB[kt * 8 + 2 * j + 1]);
            }
            const int cp = (kt * 4 + quad) ^ (lr & 7);
#pragma unroll
            for (int ni = 0; ni < 2; ++ni) {
                short8 bfr = *(const short8*)&w5s[(ni * 16 + lr) * 64 + cp * 8];
                eacc[0][ni] = __builtin_amdgcn_mfma_f32_16x16x32_bf16(sa.v, bfr, eacc[0][ni], 0, 0, 0);
                eacc[1][ni] = __builtin_amdgcn_mfma_f32_16x16x32_bf16(sb.v, bfr, eacc[1][ni], 0, 0, 0);
            }
        }
        asm volatile("s_waitcnt lgkmcnt(0)" ::: "memory");
        asm volatile("s_barrier" ::: "memory");         // w5s reusable next phase
        if (p < 7) stageW5(p + 1);
    }
    // epilogue: relu(eacc+b5), occ mask, LDS stage (pad 33), coalesced write
    float* outs = (float*)&Bsl[0];                // 128*33*4 = 16.9 KB, reuses Bsl
#pragma unroll
    for (int m = 0; m < 2; ++m)
#pragma unroll
        for (int ni = 0; ni < 2; ++ni) {
            int h = ni * 16 + lr;
            float bv = b5[h];
#pragma unroll
            for (int rr = 0; rr < 4; ++rr) {
                int cr = m * 64 + w * 16 + quad * 4 + rr;
                bool oc = offs_s[cr + 1] > offs_s[cr];
                outs[cr * 33 + h] = oc ? fmaxf(eacc[m][ni][rr] + bv, 0.f) : 0.f;
            }
        }
    __syncthreads();
#pragma unroll
    for (int m = 0; m < 2; ++m) {
        int cell = m * 64 + ln;
        if (c0 + cell < SEGR)
#pragma unroll
            for (int j = 0; j < 8; ++j)
                out[(size_t)(w * 8 + j) * NSEG + c0 + cell] = outs[cell * 33 + w * 8 + j];
    }
}

// ---- zero the gx>=360 tail of out (cells SEGR..NSEG never occur) ----
__global__ __launch_bounds__(256) void ztail_kernel(float* __restrict__ out)
{
    int i = blockIdx.x * 256 + threadIdx.x;       // grid exact: 1350*256 = 345600
    const int per = (NSEG - SEGR) / 4;            // 10800 float4 per h
    int h = i / per, c = i % per;
    *(float4*)(out + (size_t)h * NSEG + SEGR + (size_t)c * 4) = make_float4(0.f, 0.f, 0.f, 0.f);
}

extern "C" void kernel_launch(void* const* d_in, const int* in_sizes, int n_in,
                              void* d_out, int out_size, void* d_ws, size_t ws_size,
                              hipStream_t stream)
{
    const float* pt_fea = (const float*)d_in[0];
    const int*   xy_ind = (const int*)d_in[1];
    const float* bn0_g  = (const float*)d_in[2];
    const float* bn0_b  = (const float*)d_in[3];
    const float* W1     = (const float*)d_in[4];
    const float* b1     = (const float*)d_in[5];
    const float* bn1_g  = (const float*)d_in[6];
    const float* bn1_b  = (const float*)d_in[7];
    const float* W2     = (const float*)d_in[8];
    const float* b2     = (const float*)d_in[9];
    const float* bn2_g  = (const float*)d_in[10];
    const float* bn2_b  = (const float*)d_in[11];
    const float* W3     = (const float*)d_in[12];
    const float* b3     = (const float*)d_in[13];
    const float* bn3_g  = (const float*)d_in[14];
    const float* bn3_b  = (const float*)d_in[15];
    const float* W4     = (const float*)d_in[16];
    const float* b4     = (const float*)d_in[17];
    const float* W5     = (const float*)d_in[18];
    const float* b5     = (const float*)d_in[19];
    float* out = (float*)d_out;

    // ---- workspace layout (unchanged offsets; E/y4g regions now unused) ----
    const size_t oY2   = 61472768;                 // MPAD*256*2
    const size_t oE    = oY2 + (size_t)MPAD * 128 * 2;
    const size_t oCnt  = oE + (size_t)SEGR * 32 * 4;
    const size_t oOffs = oCnt + 518400;
    const size_t oCur  = oOffs + 518528;
    const size_t oOrd  = oCur + 518400;
    const size_t oCsum = oOrd + 480000;
    const size_t oSt   = oCsum + 512;
    const size_t oWt2  = oSt + 16384;
    const size_t oWt3  = oWt2 + 16384;
    const size_t oWt4  = oWt3 + 65536;
    const size_t oWt5  = oWt4 + 262144;

    unsigned short* y1   = (unsigned short*)d_ws;
    unsigned short* y3   = (unsigned short*)d_ws;
    unsigned short* y2   = (unsigned short*)((char*)d_ws + oY2);
    int*            cnt  = (int*)((char*)d_ws + oCnt);
    int*            offs = (int*)((char*)d_ws + oOffs);
    int*            cur  = (int*)((char*)d_ws + oCur);
    int*            ord  = (int*)((char*)d_ws + oOrd);
    int*            csum = (int*)((char*)d_ws + oCsum);
    float*          st   = (float*)((char*)d_ws + oSt);
    unsigned short* Wt2  = (unsigned short*)((char*)d_ws + oWt2);
    unsigned short* Wt3  = (unsigned short*)((char*)d_ws + oWt3);
    unsigned short* Wt4  = (unsigned short*)((char*)d_ws + oWt4);
    unsigned short* Wt5  = (unsigned short*)((char*)d_ws + oWt5);

    float* s0 = st + 0;     float* q0 = st + 8;
    float* W1p = st + 16;   float* b1p = st + 464;
    float* sum1 = st + 528; float* sq1 = st + 592;
    float* sum2 = st + 784; float* sq2 = st + 912;
    float* sum3 = st + 1296; float* sq3 = st + 1552;

    wtrans_kernel<<<(64 * 128 + 255) / 256, 256, 0, stream>>>(W2, Wt2, 64, 128);
    wtrans_kernel<<<(128 * 256 + 255) / 256, 256, 0, stream>>>(W3, Wt3, 128, 256);
    wtrans_kernel<<<(256 * 512 + 255) / 256, 256, 0, stream>>>(W4, Wt4, 256, 512);
    wtrans_kernel<<<(512 * 32 + 255) / 256, 256, 0, stream>>>(W5, Wt5, 512, 32);

    for (int b = 0; b < 2; ++b) {
        const float* fea_b = pt_fea + (size_t)b * NPTS * 7;
        const int*   xy_b  = xy_ind + (size_t)b * NPTS * 2;
        float*       out_b = out + (size_t)b * NHD * NSEG;

        (void)hipMemsetAsync(st, 0, 2320 * sizeof(float), stream);
        (void)hipMemsetAsync(cnt, 0, (size_t)SEGR * 4, stream);

        bn0_stats_kernel<<<128, 256, 0, stream>>>(fea_b, s0, q0);
        prep0_kernel<<<1, 64, 0, stream>>>(s0, q0, bn0_g, bn0_b, W1, b1, W1p, b1p);
        layer1_kernel<<<MPAD / 256, 256, 0, stream>>>(fea_b, W1p, b1p, y1, sum1, sq1);
        gemm_quad<64, 128, true><<<dim3(1, MB128), 256, 0, stream>>>(
            y1, Wt2, sum1, sq1, bn1_g, bn1_b, b2, y2, sum2, sq2);
        gemm_quad<128, 256, true><<<dim3(2, MB128), 256, 0, stream>>>(
            y2, Wt3, sum2, sq2, bn2_g, bn2_b, b3, y3, sum3, sq3);

        hist_kernel<<<(NPTS + 255) / 256, 256, 0, stream>>>(xy_b, cnt);
        scanA_kernel<<<64, 256, 0, stream>>>(cnt, csum);
        scanB_kernel<<<1, 64, 0, stream>>>(csum, offs);
        scanC_kernel<<<64, 256, 0, stream>>>(cnt, csum, offs, cur);
        scatter_idx_kernel<<<(NPTS + 255) / 256, 256, 0, stream>>>(xy_b, cur, ord);

        l4seg_kernel<<<(SEGR + 127) / 128, 256, 0, stream>>>(
            y3, Wt4, b4, Wt5, b5, offs, ord, sum3, sq3, bn3_g, bn3_b, out_b);
        ztail_kernel<<<1350, 256, 0, stream>>>(out_b);
    }
}

// Round 15
// 734.894 us; speedup vs baseline: 1.0100x; 1.0100x over previous
//
#include <hip/hip_runtime.h>
#include <cstdint>

#define GXD 480
#define GYD 360
#define NHD 32
#define NPTS 120000
#define MPAD 120064           // NPTS padded to multiple of 256 (469*256)
#define MB128 (MPAD/128)      // 938 M-tiles of 128 rows
#define SEGR 129600           // 360*360 possible ids
#define NSEG (GXD*GYD)        // 172800
#define EPSB 1e-5f

using short8 = __attribute__((ext_vector_type(8))) short;   // 8 bf16 in 4 VGPRs
using f32x4  = __attribute__((ext_vector_type(4))) float;   // MFMA accumulator

// ---- bf16 helpers ----
__device__ __forceinline__ float bf2f(unsigned short u) {
    return __uint_as_float(((unsigned int)u) << 16);
}
__device__ __forceinline__ unsigned short f2bf(float f) {
    unsigned int u = __float_as_uint(f);
    u += 0x7fffu + ((u >> 16) & 1u);   // round-to-nearest-even
    return (unsigned short)(u >> 16);
}
// bn+relu on a packed bf16 pair; hardware RNE pack
__device__ __forceinline__ unsigned int bnrelu_pack(unsigned int wv, float sc0, float sh0,
                                                    float sc1, float sh1)
{
    float lo = __uint_as_float(wv << 16);
    float hi = __uint_as_float(wv & 0xffff0000u);
    lo = fmaxf(fmaf(lo, sc0, sh0), 0.f);
    hi = fmaxf(fmaf(hi, sc1, sh1), 0.f);
    unsigned int r;
    asm("v_cvt_pk_bf16_f32 %0, %1, %2" : "=v"(r) : "v"(lo), "v"(hi));
    return r;
}
__device__ __forceinline__ unsigned int pk_bf16(float lo, float hi)
{
    unsigned int r;
    asm("v_cvt_pk_bf16_f32 %0, %1, %2" : "=v"(r) : "v"(lo), "v"(hi));
    return r;
}
// bn+relu applied to an 8-element bf16 A-fragment (k-ascending)
__device__ __forceinline__ short8 bn_frag(short8 a, float4 s0, float4 s1,
                                          float4 h0, float4 h1)
{
    union { short8 v; uint4 u; } in, out;
    in.v = a;
    out.u.x = bnrelu_pack(in.u.x, s0.x, h0.x, s0.y, h0.y);
    out.u.y = bnrelu_pack(in.u.y, s0.z, h0.z, s0.w, h0.w);
    out.u.z = bnrelu_pack(in.u.z, s1.x, h1.x, s1.y, h1.y);
    out.u.w = bnrelu_pack(in.u.w, s1.z, h1.z, s1.w, h1.w);
    return out.v;
}

// ---- async global->LDS, 16B per lane (dest = wave-uniform base + lane*16) ----
__device__ __forceinline__ void async16(const unsigned short* g, unsigned short* l)
{
    __builtin_amdgcn_global_load_lds(
        (const __attribute__((address_space(1))) unsigned int*)g,
        (__attribute__((address_space(3))) unsigned int*)l, 16, 0, 0);
}

// ---- bn0 stats ----
__global__ __launch_bounds__(256) void bn0_stats_kernel(
    const float* __restrict__ fea, float* __restrict__ s0, float* __restrict__ q0)
{
    float s[7] = {0,0,0,0,0,0,0}, q[7] = {0,0,0,0,0,0,0};
    for (int p = blockIdx.x * 256 + threadIdx.x; p < NPTS; p += gridDim.x * 256) {
        const float* r = fea + (size_t)p * 7;
#pragma unroll
        for (int f = 0; f < 7; ++f) { float v = r[f]; s[f] += v; q[f] += v * v; }
    }
    __shared__ float red[256];
    int t = threadIdx.x;
#pragma unroll
    for (int f = 0; f < 7; ++f) {
        red[t] = s[f]; __syncthreads();
        for (int o = 128; o > 0; o >>= 1) {
            if (t < o) red[t] += red[t + o];
            __syncthreads();
        }
        if (t == 0) atomicAdd(&s0[f], red[0]);
        __syncthreads();
        red[t] = q[f]; __syncthreads();
        for (int o = 128; o > 0; o >>= 1) {
            if (t < o) red[t] += red[t + o];
            __syncthreads();
        }
        if (t == 0) atomicAdd(&q0[f], red[0]);
        __syncthreads();
    }
}

// ---- fold bn0 into W1 ----
__global__ void prep0_kernel(const float* __restrict__ s0, const float* __restrict__ q0,
                             const float* __restrict__ g0, const float* __restrict__ b0,
                             const float* __restrict__ W1, const float* __restrict__ b1,
                             float* __restrict__ W1p, float* __restrict__ b1p)
{
    __shared__ float sc[7], sh[7];
    int t = threadIdx.x;
    if (t < 7) {
        float m = s0[t] / (float)NPTS;
        float v = q0[t] / (float)NPTS - m * m;
        float inv = 1.0f / sqrtf(fmaxf(v, 0.f) + EPSB);
        sc[t] = g0[t] * inv;
        sh[t] = b0[t] - m * g0[t] * inv;
    }
    __syncthreads();
    if (t < 64) {
        float acc = b1[t];
#pragma unroll
        for (int f = 0; f < 7; ++f) {
            W1p[f * 64 + t] = W1[f * 64 + t] * sc[f];
            acc += sh[f] * W1[f * 64 + t];
        }
        b1p[t] = acc;
    }
}

// ---- weight transpose+cast: Wt[n][k] = bf16(W[k][n]) ----
__global__ __launch_bounds__(256) void wtrans_kernel(const float* __restrict__ W,
                                                     unsigned short* __restrict__ Wt,
                                                     int K, int N)
{
    int i = blockIdx.x * 256 + threadIdx.x;
    if (i < K * N) {
        int k = i / N, n = i % N;
        Wt[(size_t)n * K + k] = f2bf(W[i]);
    }
}

// ---- layer 1: y1(bf16, raw) = fea @ W1' + b1' (K=7, Nc=64) + fp32 col stats ----
__global__ __launch_bounds__(256) void layer1_kernel(
    const float* __restrict__ fea, const float* __restrict__ W1p, const float* __restrict__ b1p,
    unsigned short* __restrict__ y1, float* __restrict__ sum1, float* __restrict__ sq1)
{
    __shared__ float Wl[448], bl[64];
    __shared__ float feaL[256 * 7];
    __shared__ float colsum[64], colsq[64];
    int t = threadIdx.x;
    int p0 = blockIdx.x * 256;
    for (int i = t; i < 448; i += 256) Wl[i] = W1p[i];
    if (t < 64) { bl[t] = b1p[t]; colsum[t] = 0.f; colsq[t] = 0.f; }
    int nval7 = (NPTS - p0) * 7;                 // valid feature words in this block
    for (int i = t; i < 256 * 7; i += 256)
        feaL[i] = (i < nval7) ? fea[(size_t)p0 * 7 + i] : 0.f;
    __syncthreads();
    int cg = t & 7, pt = t >> 3;                 // 8 col-groups x 32 point-threads
    float s[8] = {}, q[8] = {};
#pragma unroll
    for (int it = 0; it < 8; ++it) {
        int row = it * 32 + pt;
        bool valid = (p0 + row) < NPTS;
        float f[7];
#pragma unroll
        for (int ff = 0; ff < 7; ++ff) f[ff] = feaL[row * 7 + ff];
        float vj[8];
#pragma unroll
        for (int j = 0; j < 8; ++j) {
            int c = cg * 8 + j;
            float v = bl[c];
#pragma unroll
            for (int ff = 0; ff < 7; ++ff) v = fmaf(f[ff], Wl[ff * 64 + c], v);
            vj[j] = v;
            if (valid) { s[j] += v; q[j] += v * v; }
        }
        uint4 ow;
        ow.x = (unsigned int)f2bf(vj[0]) | ((unsigned int)f2bf(vj[1]) << 16);
        ow.y = (unsigned int)f2bf(vj[2]) | ((unsigned int)f2bf(vj[3]) << 16);
        ow.z = (unsigned int)f2bf(vj[4]) | ((unsigned int)f2bf(vj[5]) << 16);
        ow.w = (unsigned int)f2bf(vj[6]) | ((unsigned int)f2bf(vj[7]) << 16);
        *(uint4*)(y1 + (size_t)(p0 + row) * 64 + cg * 8) = ow;
    }
#pragma unroll
    for (int off = 8; off < 64; off <<= 1) {
#pragma unroll
        for (int j = 0; j < 8; ++j) {
            s[j] += __shfl_xor(s[j], off);
            q[j] += __shfl_xor(q[j], off);
        }
    }
    if ((t & 63) < 8) {                          // one leader per cg per wave
#pragma unroll
        for (int j = 0; j < 8; ++j) {
            atomicAdd(&colsum[cg * 8 + j], s[j]);
            atomicAdd(&colsq[cg * 8 + j], q[j]);
        }
    }
    __syncthreads();
    if (t < 64) {
        atomicAdd(&sum1[t], colsum[t]);
        atomicAdd(&sq1[t], colsq[t]);
    }
}

// ---- MFMA GEMM v18: R4 cooperative structure + in-loop bn (R6/R12-verified) ----
template<int K, int NC, bool STATS>
__global__ __launch_bounds__(256) void gemm_quad(
    const unsigned short* __restrict__ A, const unsigned short* __restrict__ Wt,
    const float* __restrict__ bsum, const float* __restrict__ bsq,
    const float* __restrict__ bg, const float* __restrict__ bb,
    const float* __restrict__ bias, unsigned short* __restrict__ Y,
    float* __restrict__ osum, float* __restrict__ osq)
{
    __shared__ __align__(16) unsigned short lds[16384];   // A[2][128][32], B[2][128][32]
    __shared__ __align__(16) float scs[K], shs[K];
    __shared__ float colsum[128], colsq[128];
    int t = threadIdx.x;
    int w = t >> 6, ln = t & 63, quad = ln >> 4, lr = ln & 15;
    int wr = w >> 1, wc = w & 1;
    const int mbase = blockIdx.y * 128;
    const int cbase = blockIdx.x * 128;
    unsigned short* Asl = lds;
    unsigned short* Bsl = lds + 8192;

    for (int i = t; i < K; i += 256) {
        float m = bsum[i] / (float)NPTS;
        float v = bsq[i] / (float)NPTS - m * m;
        float inv = 1.0f / sqrtf(fmaxf(v, 0.f) + EPSB);
        scs[i] = bg[i] * inv;
        shs[i] = bb[i] - m * bg[i] * inv;
    }
    if (STATS && t < 128) { colsum[t] = 0.f; colsq[t] = 0.f; }
    __syncthreads();                               // once, before K-loop

    const int srow = w * 16 + (ln >> 2);
    const int koff = (ln & 3) * 8;

    auto stage = [&](int buf, int kt) {
#pragma unroll
        for (int half = 0; half < 2; ++half) {
            int row = half * 64 + srow;
            async16(A  + (size_t)(mbase + row) * K + kt + koff,
                    Asl + buf * 4096 + half * 2048 + w * 512 + ln * 8);
            async16(Wt + (size_t)(cbase + row) * K + kt + koff,
                    Bsl + buf * 4096 + half * 2048 + w * 512 + ln * 8);
        }
    };

    f32x4 acc[4][4];
#pragma unroll
    for (int i = 0; i < 4; ++i)
#pragma unroll
        for (int j = 0; j < 4; ++j) acc[i][j] = (f32x4){0.f, 0.f, 0.f, 0.f};

    stage(0, 0);
    stage(1, 32);

    constexpr int NR = K / 32;
#pragma unroll
    for (int r = 0; r < NR; ++r) {
        const int buf = r & 1;
        if (r + 1 < NR)
            asm volatile("s_waitcnt vmcnt(4)" ::: "memory");
        else
            asm volatile("s_waitcnt vmcnt(0)" ::: "memory");
        asm volatile("s_barrier" ::: "memory");
        short8 af[4], bfr[4];
#pragma unroll
        for (int mi = 0; mi < 4; ++mi)
            af[mi] = *(const short8*)&Asl[buf * 4096 + (wr * 64 + mi * 16 + lr) * 32 + quad * 8];
#pragma unroll
        for (int ni = 0; ni < 4; ++ni)
            bfr[ni] = *(const short8*)&Bsl[buf * 4096 + (wc * 64 + ni * 16 + lr) * 32 + quad * 8];
        const int k0 = r * 32 + quad * 8;
        float4 s0 = *(const float4*)&scs[k0];
        float4 s1 = *(const float4*)&scs[k0 + 4];
        float4 h0 = *(const float4*)&shs[k0];
        float4 h1 = *(const float4*)&shs[k0 + 4];
        asm volatile("s_waitcnt lgkmcnt(0)" ::: "memory");
        asm volatile("s_barrier" ::: "memory");
        if (r + 2 < NR)
            stage(buf, (r + 2) * 32);
#pragma unroll
        for (int mi = 0; mi < 4; ++mi)                 // bn under the stall window
            af[mi] = bn_frag(af[mi], s0, s1, h0, h1);
#pragma unroll
        for (int mi = 0; mi < 4; ++mi)
#pragma unroll
            for (int ni = 0; ni < 4; ++ni)
                acc[mi][ni] = __builtin_amdgcn_mfma_f32_16x16x32_bf16(
                    af[mi], bfr[ni], acc[mi][ni], 0, 0, 0);
    }
    __syncthreads();

    unsigned short* Cw = lds + w * 4096;
#pragma unroll
    for (int ni = 0; ni < 4; ++ni) {
        int col = ni * 16 + lr;
        float bv = bias[cbase + wc * 64 + col];
        float s = 0.f, q = 0.f;
#pragma unroll
        for (int mi = 0; mi < 4; ++mi) {
            int rb = mi * 16 + quad * 4;
#pragma unroll
            for (int r = 0; r < 4; ++r) {
                float v = acc[mi][ni][r] + bv;
                Cw[(rb + r) * 64 + col] = f2bf(v);
                if (STATS && (mbase + wr * 64 + rb + r) < NPTS) { s += v; q += v * v; }
            }
        }
        if (STATS) {
            atomicAdd(&colsum[wc * 64 + col], s);
            atomicAdd(&colsq[wc * 64 + col], q);
        }
    }
#pragma unroll
    for (int i = 0; i < 8; ++i) {
        int idx = i * 64 + ln;
        int row = idx >> 3, colq = (idx & 7) * 8;
        *(uint4*)(Y + (size_t)(mbase + wr * 64 + row) * NC + cbase + wc * 64 + colq) =
            *(const uint4*)&Cw[row * 64 + colq];
    }
    if (STATS) {
        __syncthreads();
        if (t < 128) {
            atomicAdd(&osum[blockIdx.x * 128 + t], colsum[t]);
            atomicAdd(&osq[blockIdx.x * 128 + t], colsq[t]);
        }
    }
}

// ---- sort machinery: histogram, 3-phase exclusive scan, index scatter ----
__global__ __launch_bounds__(256) void hist_kernel(const int* __restrict__ xy,
                                                   int* __restrict__ cnt)
{
    int p = blockIdx.x * 256 + threadIdx.x;
    if (p < NPTS) {
        int id = xy[(size_t)p * 2] * GYD + xy[(size_t)p * 2 + 1];
        atomicAdd(&cnt[id], 1);
    }
}

__global__ __launch_bounds__(256) void scanA_kernel(const int* __restrict__ cnt,
                                                    int* __restrict__ csum)
{
    __shared__ int red[256];
    int t = threadIdx.x, base = blockIdx.x * 2048;
    int s = 0;
    for (int i = t; i < 2048; i += 256) {
        int idx = base + i;
        if (idx < SEGR) s += cnt[idx];
    }
    red[t] = s; __syncthreads();
    for (int o = 128; o > 0; o >>= 1) { if (t < o) red[t] += red[t + o]; __syncthreads(); }
    if (t == 0) csum[blockIdx.x] = red[0];
}

__global__ void scanB_kernel(int* __restrict__ csum, int* __restrict__ offs)
{
    if (threadIdx.x == 0) {
        int run = 0;
        for (int i = 0; i < 64; ++i) { int v = csum[i]; csum[i] = run; run += v; }
        offs[SEGR] = run;
    }
}

__global__ __launch_bounds__(256) void scanC_kernel(const int* __restrict__ cnt,
                                                    const int* __restrict__ csum,
                                                    int* __restrict__ offs,
                                                    int* __restrict__ cursor)
{
    __shared__ int red[256];
    int t = threadIdx.x, base = blockIdx.x * 2048;
    int v[8]; int s = 0;
#pragma unroll
    for (int i = 0; i < 8; ++i) {
        int idx = base + t * 8 + i;
        v[i] = (idx < SEGR) ? cnt[idx] : 0;
        s += v[i];
    }
    red[t] = s; __syncthreads();
    for (int o = 1; o < 256; o <<= 1) {
        int x = (t >= o) ? red[t - o] : 0;
        __syncthreads();
        red[t] += x;
        __syncthreads();
    }
    int run = red[t] - s + csum[blockIdx.x];
#pragma unroll
    for (int i = 0; i < 8; ++i) {
        int idx = base + t * 8 + i;
        if (idx < SEGR) { offs[idx] = run; cursor[idx] = run; }
        run += v[i];
    }
}

__global__ __launch_bounds__(256) void scatter_idx_kernel(const int* __restrict__ xy,
                                                          int* __restrict__ cursor,
                                                          int* __restrict__ order)
{
    int p = blockIdx.x * 256 + threadIdx.x;
    if (p < NPTS) {
        int id = xy[(size_t)p * 2] * GYD + xy[(size_t)p * 2 + 1];
        int pos = atomicAdd(&cursor[id], 1);
        order[pos] = p;
    }
}

// ---- FUSED L4+segmax+W5+output v5 (R12-verified) + T5 setprio on MFMA ----
// Co-resident INDEPENDENT blocks sit at different phases, so boosting the
// MFMA-cluster wave's priority lets it preempt another block's staging waves
// (m191 regime; the m190 null was lockstep same-block waves).
__global__ __launch_bounds__(256) void l4seg_kernel(
    const unsigned short* __restrict__ y3, const unsigned short* __restrict__ Wt4,
    const float* __restrict__ b4, const unsigned short* __restrict__ Wt5,
    const float* __restrict__ b5, const int* __restrict__ offs,
    const int* __restrict__ ord,
    const float* __restrict__ bsum, const float* __restrict__ bsq,
    const float* __restrict__ bg, const float* __restrict__ bb,
    float* __restrict__ out)
{
    __shared__ __align__(16) unsigned short Bsl[64 * 256];    // 32 KB
    __shared__ __align__(16) unsigned short w5s[32 * 64];     // 4 KB
    __shared__ __align__(16) unsigned short y4s[64 * 72];     // 9 KB (y4 chunk / seg)
    __shared__ float b4s[512];
    __shared__ float scs[256], shs[256];
    __shared__ int offs_s[65];
    __shared__ int osl[128];
    int t = threadIdx.x;
    int w = t >> 6, ln = t & 63, quad = ln >> 4, lr = ln & 15;
    int c0 = blockIdx.x * 64;
    if (t < 65) offs_s[t] = offs[c0 + t];
    for (int i = t; i < 512; i += 256) b4s[i] = b4[i];
    __syncthreads();
    const int jb = offs_s[0], je = offs_s[64];
    if (jb == je) {                               // whole block empty -> zeros
#pragma unroll
        for (int j = 0; j < 8; ++j)
            out[(size_t)(w * 8 + j) * NSEG + c0 + ln] = 0.f;
        return;
    }
    {   // bn3 scale/shift for the 256 input channels (one per thread)
        float m = bsum[t] / (float)NPTS;
        float v = bsq[t] / (float)NPTS - m * m;
        float inv = 1.0f / sqrtf(fmaxf(v, 0.f) + EPSB);
        scs[t] = bg[t] * inv;
        shs[t] = bb[t] - m * bg[t] * inv;
    }
    if (t < 128) { int aj = jb + t; osl[t] = (aj < je) ? ord[aj] : 0; }
    __syncthreads();

    const int cell = t >> 2, q = t & 3;
    const int cjb = offs_s[cell], cje = offs_s[cell + 1];
    const int nch = (je - jb + 63) >> 6;

    // ---- resident A (bn+relu applied once): chunks 0 and 1 ----
    short8 af0[8], af1[8];
    {
        int j0 = w * 16 + lr; if (jb + j0 >= je) j0 = je - 1 - jb;
        const unsigned short* Ar0 = y3 + (size_t)osl[j0] * 256 + quad * 8;
#pragma unroll
        for (int r = 0; r < 8; ++r) af0[r] = *(const short8*)(Ar0 + r * 32);
        int j1 = 64 + w * 16 + lr; if (jb + j1 >= je) j1 = je - 1 - jb;
        const unsigned short* Ar1 = y3 + (size_t)osl[j1] * 256 + quad * 8;
#pragma unroll
        for (int r = 0; r < 8; ++r) af1[r] = *(const short8*)(Ar1 + r * 32);
#pragma unroll
        for (int r = 0; r < 8; ++r) {
            const int k0 = r * 32 + quad * 8;
            float4 s0 = *(const float4*)&scs[k0];
            float4 s1 = *(const float4*)&scs[k0 + 4];
            float4 h0 = *(const float4*)&shs[k0];
            float4 h1 = *(const float4*)&shs[k0 + 4];
            af0[r] = bn_frag(af0[r], s0, s1, h0, h1);
            af1[r] = bn_frag(af1[r], s0, s1, h0, h1);
        }
    }

    f32x4 eacc[2];
    eacc[0] = (f32x4){0.f, 0.f, 0.f, 0.f};
    eacc[1] = (f32x4){0.f, 0.f, 0.f, 0.f};

    auto stageB = [&](int p) {
#pragma unroll
        for (int i = 0; i < 8; ++i) {
            int rl = w * 16 + i * 2 + (ln >> 5);            // local B row 0..63
            int cl = (ln & 31) ^ (rl & 7);                  // source logical chunk
            async16(Wt4 + (size_t)(p * 64 + rl) * 256 + cl * 8,
                    Bsl + (w * 16 + i * 2) * 256 + ln * 8);
        }
    };
    auto stageW5 = [&](int p) {
        int rl = t >> 3, cl = (t & 7) ^ (rl & 7);
        async16(Wt5 + (size_t)rl * 512 + p * 64 + cl * 8, w5s + t * 8);
    };
    auto mfma_chunk = [&](const short8* af, f32x4* acc) {
        __builtin_amdgcn_s_setprio(1);
#pragma unroll
        for (int r = 0; r < 8; ++r) {
            const int cp = (r * 4 + quad) ^ (lr & 7);
#pragma unroll
            for (int ni = 0; ni < 4; ++ni) {
                short8 bfr = *(const short8*)&Bsl[(ni * 16 + lr) * 256 + cp * 8];
                acc[ni] = __builtin_amdgcn_mfma_f32_16x16x32_bf16(af[r], bfr, acc[ni], 0, 0, 0);
            }
        }
        __builtin_amdgcn_s_setprio(0);
    };

    stageB(0); stageW5(0);

    for (int p = 0; p < 8; ++p) {
        asm volatile("s_waitcnt vmcnt(0)" ::: "memory");    // B(p), w5(p) landed
        asm volatile("s_barrier" ::: "memory");
        float mxv[16];
#pragma unroll
        for (int i = 0; i < 16; ++i) mxv[i] = -3.0e38f;

        for (int c = 0; c < nch; ++c) {
            const int cs = jb + c * 64;
            f32x4 acc[4];
#pragma unroll
            for (int i = 0; i < 4; ++i) acc[i] = (f32x4){0.f, 0.f, 0.f, 0.f};
            if (c == 0) {
                mfma_chunk(af0, acc);
            } else if (c == 1) {
                mfma_chunk(af1, acc);
            } else {                                   // rare: >128 pts in block
                int j = cs + w * 16 + lr; if (j >= je) j = je - 1;
                const unsigned short* Ar = y3 + (size_t)ord[j] * 256 + quad * 8;
#pragma unroll
                for (int r = 0; r < 8; ++r) {
                    short8 a = *(const short8*)(Ar + r * 32);
                    const int k0 = r * 32 + quad * 8;
                    float4 s0 = *(const float4*)&scs[k0];
                    float4 s1 = *(const float4*)&scs[k0 + 4];
                    float4 h0 = *(const float4*)&shs[k0];
                    float4 h1 = *(const float4*)&shs[k0 + 4];
                    a = bn_frag(a, s0, s1, h0, h1);
                    const int cp = (r * 4 + quad) ^ (lr & 7);
#pragma unroll
                    for (int ni = 0; ni < 4; ++ni) {
                        short8 bfr = *(const short8*)&Bsl[(ni * 16 + lr) * 256 + cp * 8];
                        acc[ni] = __builtin_amdgcn_mfma_f32_16x16x32_bf16(a, bfr, acc[ni], 0, 0, 0);
                    }
                }
            }
            // y4 (+b4) -> y4s  (row = chunk-local point, col = phase col)
#pragma unroll
            for (int ni = 0; ni < 4; ++ni) {
                float bv = b4s[p * 64 + ni * 16 + lr];
#pragma unroll
                for (int rr = 0; rr < 4; ++rr)
                    y4s[(w * 16 + quad * 4 + rr) * 72 + ni * 16 + lr] = f2bf(acc[ni][rr] + bv);
            }
            asm volatile("s_waitcnt lgkmcnt(0)" ::: "memory");
            asm volatile("s_barrier" ::: "memory");     // all waves past MFMA + y4s write
            if (c == nch - 1 && p < 7)
                stageB(p + 1);                          // Bsl free: overlap with max+seg
            // per-cell running max (thread: cell x 16 cols of this phase)
            int lo = cjb > cs ? cjb : cs;
            int hi = cje < cs + 64 ? cje : cs + 64;
            for (int jj = lo; jj < hi; ++jj) {
                const uint4* rp = (const uint4*)&y4s[(jj - cs) * 72 + q * 16];
                uint4 v0 = rp[0], v1 = rp[1];
                unsigned int wv[8] = {v0.x, v0.y, v0.z, v0.w, v1.x, v1.y, v1.z, v1.w};
#pragma unroll
                for (int k2 = 0; k2 < 8; ++k2) {
                    mxv[2 * k2]     = fmaxf(mxv[2 * k2],     bf2f((unsigned short)(wv[k2] & 0xffffu)));
                    mxv[2 * k2 + 1] = fmaxf(mxv[2 * k2 + 1], bf2f((unsigned short)(wv[k2] >> 16)));
                }
            }
            asm volatile("s_barrier" ::: "memory");     // y4s free (next chunk / seg)
        }
        // seg -> y4s (empty cells -> 0, scatter semantics)
        {
            bool empty = (cjb == cje);
#pragma unroll
            for (int i = 0; i < 8; ++i) {
                float lo2 = empty ? 0.f : mxv[2 * i], hi2 = empty ? 0.f : mxv[2 * i + 1];
                *(unsigned int*)&y4s[cell * 72 + q * 16 + 2 * i] = pk_bf16(lo2, hi2);
            }
        }
        asm volatile("s_waitcnt lgkmcnt(0)" ::: "memory");
        asm volatile("s_barrier" ::: "memory");
        // E += seg @ W5 slice  (cells 64 x heads 32, k=64)
        __builtin_amdgcn_s_setprio(1);
#pragma unroll
        for (int kt = 0; kt < 2; ++kt) {
            short8 af2 = *(const short8*)&y4s[(w * 16 + lr) * 72 + kt * 32 + quad * 8];
            const int cp = (kt * 4 + quad) ^ (lr & 7);
#pragma unroll
            for (int ni = 0; ni < 2; ++ni) {
                short8 bfr = *(const short8*)&w5s[(ni * 16 + lr) * 64 + cp * 8];
                eacc[ni] = __builtin_amdgcn_mfma_f32_16x16x32_bf16(af2, bfr, eacc[ni], 0, 0, 0);
            }
        }
        __builtin_amdgcn_s_setprio(0);
        asm volatile("s_waitcnt lgkmcnt(0)" ::: "memory");
        asm volatile("s_barrier" ::: "memory");         // w5s/y4s reusable next phase
        if (p < 7) stageW5(p + 1);
    }
    // epilogue: relu(eacc+b5), occ mask, LDS stage (pad 33), coalesced write
    float* outs = (float*)&Bsl[0];                // 64*33*4 = 8448 B, reuses Bsl
#pragma unroll
    for (int ni = 0; ni < 2; ++ni) {
        int h = ni * 16 + lr;
        float bv = b5[h];
#pragma unroll
        for (int rr = 0; rr < 4; ++rr) {
            int cr = w * 16 + quad * 4 + rr;
            bool oc = offs_s[cr + 1] > offs_s[cr];
            outs[cr * 33 + h] = oc ? fmaxf(eacc[ni][rr] + bv, 0.f) : 0.f;
        }
    }
    __syncthreads();
#pragma unroll
    for (int j = 0; j < 8; ++j)
        out[(size_t)(w * 8 + j) * NSEG + c0 + ln] = outs[ln * 33 + w * 8 + j];
}

// ---- zero the gx>=360 tail of out (cells SEGR..NSEG never occur) ----
__global__ __launch_bounds__(256) void ztail_kernel(float* __restrict__ out)
{
    int i = blockIdx.x * 256 + threadIdx.x;       // grid exact: 1350*256 = 345600
    const int per = (NSEG - SEGR) / 4;            // 10800 float4 per h
    int h = i / per, c = i % per;
    *(float4*)(out + (size_t)h * NSEG + SEGR + (size_t)c * 4) = make_float4(0.f, 0.f, 0.f, 0.f);
}

extern "C" void kernel_launch(void* const* d_in, const int* in_sizes, int n_in,
                              void* d_out, int out_size, void* d_ws, size_t ws_size,
                              hipStream_t stream)
{
    const float* pt_fea = (const float*)d_in[0];
    const int*   xy_ind = (const int*)d_in[1];
    const float* bn0_g  = (const float*)d_in[2];
    const float* bn0_b  = (const float*)d_in[3];
    const float* W1     = (const float*)d_in[4];
    const float* b1     = (const float*)d_in[5];
    const float* bn1_g  = (const float*)d_in[6];
    const float* bn1_b  = (const float*)d_in[7];
    const float* W2     = (const float*)d_in[8];
    const float* b2     = (const float*)d_in[9];
    const float* bn2_g  = (const float*)d_in[10];
    const float* bn2_b  = (const float*)d_in[11];
    const float* W3     = (const float*)d_in[12];
    const float* b3     = (const float*)d_in[13];
    const float* bn3_g  = (const float*)d_in[14];
    const float* bn3_b  = (const float*)d_in[15];
    const float* W4     = (const float*)d_in[16];
    const float* b4     = (const float*)d_in[17];
    const float* W5     = (const float*)d_in[18];
    const float* b5     = (const float*)d_in[19];
    float* out = (float*)d_out;

    // ---- workspace layout (unchanged offsets) ----
    const size_t oY2   = 61472768;                 // MPAD*256*2
    const size_t oE    = oY2 + (size_t)MPAD * 128 * 2;
    const size_t oCnt  = oE + (size_t)SEGR * 32 * 4;
    const size_t oOffs = oCnt + 518400;
    const size_t oCur  = oOffs + 518528;
    const size_t oOrd  = oCur + 518400;
    const size_t oCsum = oOrd + 480000;
    const size_t oSt   = oCsum + 512;
    const size_t oWt2  = oSt + 16384;
    const size_t oWt3  = oWt2 + 16384;
    const size_t oWt4  = oWt3 + 65536;
    const size_t oWt5  = oWt4 + 262144;

    unsigned short* y1   = (unsigned short*)d_ws;
    unsigned short* y3   = (unsigned short*)d_ws;
    unsigned short* y2   = (unsigned short*)((char*)d_ws + oY2);
    int*            cnt  = (int*)((char*)d_ws + oCnt);
    int*            offs = (int*)((char*)d_ws + oOffs);
    int*            cur  = (int*)((char*)d_ws + oCur);
    int*            ord  = (int*)((char*)d_ws + oOrd);
    int*            csum = (int*)((char*)d_ws + oCsum);
    float*          st   = (float*)((char*)d_ws + oSt);
    unsigned short* Wt2  = (unsigned short*)((char*)d_ws + oWt2);
    unsigned short* Wt3  = (unsigned short*)((char*)d_ws + oWt3);
    unsigned short* Wt4  = (unsigned short*)((char*)d_ws + oWt4);
    unsigned short* Wt5  = (unsigned short*)((char*)d_ws + oWt5);

    float* s0 = st + 0;     float* q0 = st + 8;
    float* W1p = st + 16;   float* b1p = st + 464;
    float* sum1 = st + 528; float* sq1 = st + 592;
    float* sum2 = st + 784; float* sq2 = st + 912;
    float* sum3 = st + 1296; float* sq3 = st + 1552;

    wtrans_kernel<<<(64 * 128 + 255) / 256, 256, 0, stream>>>(W2, Wt2, 64, 128);
    wtrans_kernel<<<(128 * 256 + 255) / 256, 256, 0, stream>>>(W3, Wt3, 128, 256);
    wtrans_kernel<<<(256 * 512 + 255) / 256, 256, 0, stream>>>(W4, Wt4, 256, 512);
    wtrans_kernel<<<(512 * 32 + 255) / 256, 256, 0, stream>>>(W5, Wt5, 512, 32);

    for (int b = 0; b < 2; ++b) {
        const float* fea_b = pt_fea + (size_t)b * NPTS * 7;
        const int*   xy_b  = xy_ind + (size_t)b * NPTS * 2;
        float*       out_b = out + (size_t)b * NHD * NSEG;

        (void)hipMemsetAsync(st, 0, 2320 * sizeof(float), stream);
        (void)hipMemsetAsync(cnt, 0, (size_t)SEGR * 4, stream);

        bn0_stats_kernel<<<128, 256, 0, stream>>>(fea_b, s0, q0);
        prep0_kernel<<<1, 64, 0, stream>>>(s0, q0, bn0_g, bn0_b, W1, b1, W1p, b1p);
        layer1_kernel<<<MPAD / 256, 256, 0, stream>>>(fea_b, W1p, b1p, y1, sum1, sq1);
        gemm_quad<64, 128, true><<<dim3(1, MB128), 256, 0, stream>>>(
            y1, Wt2, sum1, sq1, bn1_g, bn1_b, b2, y2, sum2, sq2);
        gemm_quad<128, 256, true><<<dim3(2, MB128), 256, 0, stream>>>(
            y2, Wt3, sum2, sq2, bn2_g, bn2_b, b3, y3, sum3, sq3);

        hist_kernel<<<(NPTS + 255) / 256, 256, 0, stream>>>(xy_b, cnt);
        scanA_kernel<<<64, 256, 0, stream>>>(cnt, csum);
        scanB_kernel<<<1, 64, 0, stream>>>(csum, offs);
        scanC_kernel<<<64, 256, 0, stream>>>(cnt, csum, offs, cur);
        scatter_idx_kernel<<<(NPTS + 255) / 256, 256, 0, stream>>>(xy_b, cur, ord);

        l4seg_kernel<<<SEGR / 64, 256, 0, stream>>>(
            y3, Wt4, b4, Wt5, b5, offs, ord, sum3, sq3, bn3_g, bn3_b, out_b);
        ztail_kernel<<<1350, 256, 0, stream>>>(out_b);
    }
}